// Round 5
// baseline (543.772 us; speedup 1.0000x reference)
//
#include <hip/hip_runtime.h>
#include <stdint.h>

// BinHD: samples [8192,10000] f32 {0,1}, classes [1000,10000] f32 {0,1}
// out [8192,1000] f32 = exact Hamming distance.
// v5: same i8-MFMA {0,1} algorithm as v4; occupancy restructure:
//   tile 128x64, grid 64x16 = 1024 blocks = 4 blocks/CU = 4 waves/SIMD
//   (v4 had 2 waves/SIMD; UNP->MFMA dep chains serialized the pipes).
#define N_ROWS 8192
#define C_CLS  1000
#define D_DIM  10000
#define W64P   160            // u64 words per packed row (pad bits are 0)
#define W32P   (W64P * 2)     // 320 u32 words per packed row
#define BKW    16             // u32 words per row per chunk (512 dims)
#define NCHUNK 20             // 20 * 16 = 320 words

typedef int v4i  __attribute__((ext_vector_type(4)));
typedef int v16i __attribute__((ext_vector_type(16)));

// ---------------------------------------------------------------------------
// Kernel 1 (unchanged, proven, HBM-bound at ~58 us floor): bit-pack fp32
// {0,1} rows into u64 words + per-row popcount. Fixed dim permutation
// identical for A and B => dot invariant. Writes ALL 160 words/row + rowsum
// -> poisoned ws regions we later read are fully initialized.
// ---------------------------------------------------------------------------
__global__ __launch_bounds__(256) void pack_kernel(
    const float* __restrict__ samples, const float* __restrict__ classes,
    unsigned long long* __restrict__ pA, unsigned long long* __restrict__ pB,
    uint32_t* __restrict__ rsA, uint32_t* __restrict__ rsB)
{
    int gwave = (blockIdx.x * 256 + threadIdx.x) >> 6;
    int lane  = threadIdx.x & 63;
    if (gwave >= N_ROWS + C_CLS) return;   // wave-uniform exit

    const float* src;
    unsigned long long* dst;
    uint32_t* rsw;
    if (gwave < N_ROWS) {
        src = samples + (size_t)gwave * D_DIM;
        dst = pA + (size_t)gwave * W64P;
        rsw = rsA + gwave;
    } else {
        int r = gwave - N_ROWS;
        src = classes + (size_t)r * D_DIM;
        dst = pB + (size_t)r * W64P;
        rsw = rsB + r;
    }

    uint32_t rs = 0;
    #pragma unroll 4
    for (int w = 0; w < 40; ++w) {         // 40 * 4 = 160 u64 words
        int idx = w * 256 + lane * 4;      // 16B/lane, coalesced 1KB/wave
        float4 v = make_float4(0.f, 0.f, 0.f, 0.f);
        if (idx < D_DIM) v = *(const float4*)(src + idx);   // D_DIM%4==0
        unsigned long long m0 = __ballot(v.x > 0.5f);
        unsigned long long m1 = __ballot(v.y > 0.5f);
        unsigned long long m2 = __ballot(v.z > 0.5f);
        unsigned long long m3 = __ballot(v.w > 0.5f);
        rs += (uint32_t)(__popcll(m0) + __popcll(m1) + __popcll(m2) + __popcll(m3));
        if (lane == 0) {
            uint4 p0, p1;
            p0.x = (uint32_t)m0; p0.y = (uint32_t)(m0 >> 32);
            p0.z = (uint32_t)m1; p0.w = (uint32_t)(m1 >> 32);
            p1.x = (uint32_t)m2; p1.y = (uint32_t)(m2 >> 32);
            p1.z = (uint32_t)m3; p1.w = (uint32_t)(m3 >> 32);
            *(uint4*)(dst + (size_t)w * 4)     = p0;
            *(uint4*)(dst + (size_t)w * 4 + 2) = p1;
        }
    }
    if (lane == 0) *rsw = rs;
}

// ---------------------------------------------------------------------------
// Kernel 2: dot01 GEMM on matrix cores (v_mfma_i32_32x32x32_i8, {0,1} bytes).
// Block: 256 thr (4 waves), tile 128x64; wave tile 64x32 = 2 accs (64 VGPR->32).
// Grid 64x16 = 1024 blocks -> 4 blocks/CU -> 16 waves/CU = 4 waves/SIMD:
// other waves' MFMAs hide each wave's UNP chain (v4 was 2/SIMD, serialized).
// K: 20 chunks of 512 dims. LDS: packed bits, paired-transpose [pair][row][2]
// (A 8 KB, B 4 KB per buf; dbuf = 24 KB -> 4 blocks fit 96 KB/CU).
//   reads:  ds_read_b64 (2 K-steps); rows stride 8 B -> 2-way + bcast (free)
//   writes: A 4x + B 2x ds_write_b64 per thread per chunk
// Unpack {0,1}: reg j = (word >> (h4+j)) & 0x01010101 (2 VALU/reg).
// Per-SIMD/chunk budget: MFMA 4685 cyc (floor) > VALU 3072 > LDS ~2200.
// Reg-staged global->LDS issued before compute (T14), ONE barrier per chunk.
// ---------------------------------------------------------------------------
__global__ __launch_bounds__(256) void hd_kernel(
    const uint32_t* __restrict__ pA, const uint32_t* __restrict__ pB,
    const uint32_t* __restrict__ rsA, const uint32_t* __restrict__ rsB,
    float* __restrict__ out)
{
    __shared__ uint32_t AsT[2][(BKW / 2) * 256];   // [buf][pair*256 + row*2 + sub]
    __shared__ uint32_t BsT[2][(BKW / 2) * 128];   // [buf][pair*128 + col*2 + sub]

    const int tid  = threadIdx.x;
    const int row0 = blockIdx.x * 128;       // 64 row tiles
    const int col0 = blockIdx.y * 64;        // 16 col tiles (1024 padded)

    const int w    = tid >> 6;               // wave 0..3
    const int lane = tid & 63;
    const int wy   = w >> 1;                 // wave row half: rows wy*64..+63
    const int wx   = w & 1;                  // wave col half: cols wx*32..+31
    const int ln   = lane & 31;              // row/col within 32-tile
    const int h4   = (lane >> 5) * 4;        // k-half shift base

    // A staging: thread covers row srow = tid>>1, word-octet sq2 = (tid&1)*2.
    const int srow = tid >> 1;               // 0..127
    const int sq2  = (tid & 1) * 2;
    const uint32_t* gAs = pA + (size_t)(row0 + srow) * W32P + sq2 * 4;
    // B staging: thread covers col rb = tid>>2, word-quad qb = tid&3.
    const int rb   = tid >> 2;               // 0..63
    const int qb   = tid & 3;
    int gc = col0 + rb; if (gc >= C_CLS) gc = C_CLS - 1;  // clamped cols never stored
    const uint32_t* gBs = pB + (size_t)gc * W32P + qb * 4;

    uint4 av[2], bv;                         // in-flight staging regs (T14)

#define LOADR(ch) do {                                             \
    av[0] = *(const uint4*)(gAs + (ch) * BKW);                     \
    av[1] = *(const uint4*)(gAs + (ch) * BKW + 4);                 \
    bv    = *(const uint4*)(gBs + (ch) * BKW);                     \
} while (0)

    // A: steps sq2*4+0..7 -> pairs sq2*2+i, i=0..3, slot [pair*256 + srow*2]
    // B: steps qb*4+0..3  -> pairs qb*2+i,  i=0..1, slot [pair*128 + rb*2]
#define WRITELDS(buf) do {                                         \
    uint32_t* ap_ = &AsT[buf][sq2 * 512 + srow * 2];               \
    *(uint2*)(ap_      ) = make_uint2(av[0].x, av[0].y);           \
    *(uint2*)(ap_ + 256) = make_uint2(av[0].z, av[0].w);           \
    *(uint2*)(ap_ + 512) = make_uint2(av[1].x, av[1].y);           \
    *(uint2*)(ap_ + 768) = make_uint2(av[1].z, av[1].w);           \
    uint32_t* bp_ = &BsT[buf][qb * 256 + rb * 2];                  \
    *(uint2*)(bp_      ) = make_uint2(bv.x, bv.y);                 \
    *(uint2*)(bp_ + 128) = make_uint2(bv.z, bv.w);                 \
} while (0)

    // bit-word -> 16 x i8 {0,1} fragment (lane's k-half selected by h4)
#define UNP(dst, src) do {                                         \
    dst[0] = (int)(((src) >> (h4 + 0)) & 0x01010101u);             \
    dst[1] = (int)(((src) >> (h4 + 1)) & 0x01010101u);             \
    dst[2] = (int)(((src) >> (h4 + 2)) & 0x01010101u);             \
    dst[3] = (int)(((src) >> (h4 + 3)) & 0x01010101u);             \
} while (0)

    v16i acc0 = {}, acc1 = {};               // rows wy*64+m, wy*64+32+m

    LOADR(0);
    WRITELDS(0);
    __syncthreads();

    #pragma unroll 2
    for (int ch = 0; ch < NCHUNK; ++ch) {
        const int cur = ch & 1;
        if (ch + 1 < NCHUNK) LOADR(ch + 1);   // issue early; consumed after compute

        const uint32_t* Ac = &AsT[cur][0];
        const uint32_t* Bc = &BsT[cur][0];

        #pragma unroll
        for (int p = 0; p < BKW / 2; ++p) {   // one b64 = 2 K-steps
            uint2 wa0 = *(const uint2*)&Ac[p * 256 + (wy * 64 + ln) * 2];
            uint2 wa1 = *(const uint2*)&Ac[p * 256 + (wy * 64 + 32 + ln) * 2];
            uint2 wb  = *(const uint2*)&Bc[p * 128 + (wx * 32 + ln) * 2];
            v4i a0, a1, b;
            UNP(a0, wa0.x); UNP(a1, wa1.x); UNP(b, wb.x);
            acc0 = __builtin_amdgcn_mfma_i32_32x32x32_i8(a0, b, acc0, 0, 0, 0);
            acc1 = __builtin_amdgcn_mfma_i32_32x32x32_i8(a1, b, acc1, 0, 0, 0);
            UNP(a0, wa0.y); UNP(a1, wa1.y); UNP(b, wb.y);
            acc0 = __builtin_amdgcn_mfma_i32_32x32x32_i8(a0, b, acc0, 0, 0, 0);
            acc1 = __builtin_amdgcn_mfma_i32_32x32x32_i8(a1, b, acc1, 0, 0, 0);
        }

        if (ch + 1 < NCHUNK) {
            WRITELDS((ch + 1) & 1);   // other buffer: disjoint from cur readers
            __syncthreads();          // writes visible before next chunk's reads
        }
    }
#undef LOADR
#undef WRITELDS
#undef UNP

    // ---- epilogue: dist = rsA + rsB - 2*dot01, exact integer -> f32.
    // C/D layout (32x32): col = lane&31, row = (r&3) + 8*(r>>2) + 4*(lane>>5)
    const int gcol = col0 + wx * 32 + ln;
    const uint32_t rbv = (gcol < C_CLS) ? rsB[gcol] : 0u;
    if (gcol < C_CLS) {
        #pragma unroll
        for (int r = 0; r < 16; ++r) {
            const int m    = (r & 3) + 8 * (r >> 2) + h4;
            const int rowa = row0 + wy * 64 + m;
            const int rowb = rowa + 32;
            out[(size_t)rowa * C_CLS + gcol] =
                (float)(int)(rsA[rowa] + rbv - 2u * (uint32_t)acc0[r]);
            out[(size_t)rowb * C_CLS + gcol] =
                (float)(int)(rsA[rowb] + rbv - 2u * (uint32_t)acc1[r]);
        }
    }
}

extern "C" void kernel_launch(void* const* d_in, const int* in_sizes, int n_in,
                              void* d_out, int out_size, void* d_ws, size_t ws_size,
                              hipStream_t stream) {
    const float* samples = (const float*)d_in[0];   // [8192, 10000] f32
    const float* classes = (const float*)d_in[1];   // [1000, 10000] f32
    float* out = (float*)d_out;                     // [8192, 1000] f32

    // Workspace: packed A (10.49 MB), packed B (1.28 MB), rowsums (36.8 KB).
    unsigned long long* pA = (unsigned long long*)d_ws;
    unsigned long long* pB = pA + (size_t)N_ROWS * W64P;
    uint32_t* rsA = (uint32_t*)(pB + (size_t)C_CLS * W64P);
    uint32_t* rsB = rsA + N_ROWS;

    int waves  = N_ROWS + C_CLS;
    int blocks = (waves + 3) / 4;
    pack_kernel<<<blocks, 256, 0, stream>>>(samples, classes, pA, pB, rsA, rsB);

    dim3 grid(N_ROWS / 128, 16);             // 1024 blocks -> 4 blocks/CU
    hd_kernel<<<grid, 256, 0, stream>>>((const uint32_t*)pA, (const uint32_t*)pB,
                                        rsA, rsB, out);
}

// Round 6
// 543.598 us; speedup vs baseline: 1.0003x; 1.0003x over previous
//
#include <hip/hip_runtime.h>
#include <stdint.h>

// BinHD: samples [8192,10000] f32 {0,1}, classes [1000,10000] f32 {0,1}
// out [8192,1000] f32 = exact Hamming distance.
// v6: v4 geometry (64x64 wave tile, 2x2 accs, 8 VALU/MFMA) + anti-serialization:
//   explicit 1-pair-ahead LDS read pipeline, fine UNP/MFMA interleave,
//   setprio around compute clusters, per-wave pair-order skew.
#define N_ROWS 8192
#define C_CLS  1000
#define D_DIM  10000
#define W64P   160            // u64 words per packed row (pad bits are 0)
#define W32P   (W64P * 2)     // 320 u32 words per packed row
#define BKW    16             // u32 words per row per chunk (512 dims)
#define NCHUNK 20             // 20 * 16 = 320 words

typedef int v4i  __attribute__((ext_vector_type(4)));
typedef int v16i __attribute__((ext_vector_type(16)));

// ---------------------------------------------------------------------------
// Kernel 1 (unchanged, proven, ~HBM floor): bit-pack fp32 {0,1} rows into u64
// words + per-row popcount. Fixed dim permutation identical for A and B =>
// dot invariant. Writes ALL 160 words/row + rowsum -> poisoned ws regions we
// later read are fully initialized.
// ---------------------------------------------------------------------------
__global__ __launch_bounds__(256) void pack_kernel(
    const float* __restrict__ samples, const float* __restrict__ classes,
    unsigned long long* __restrict__ pA, unsigned long long* __restrict__ pB,
    uint32_t* __restrict__ rsA, uint32_t* __restrict__ rsB)
{
    int gwave = (blockIdx.x * 256 + threadIdx.x) >> 6;
    int lane  = threadIdx.x & 63;
    if (gwave >= N_ROWS + C_CLS) return;   // wave-uniform exit

    const float* src;
    unsigned long long* dst;
    uint32_t* rsw;
    if (gwave < N_ROWS) {
        src = samples + (size_t)gwave * D_DIM;
        dst = pA + (size_t)gwave * W64P;
        rsw = rsA + gwave;
    } else {
        int r = gwave - N_ROWS;
        src = classes + (size_t)r * D_DIM;
        dst = pB + (size_t)r * W64P;
        rsw = rsB + r;
    }

    uint32_t rs = 0;
    #pragma unroll 4
    for (int w = 0; w < 40; ++w) {         // 40 * 4 = 160 u64 words
        int idx = w * 256 + lane * 4;      // 16B/lane, coalesced 1KB/wave
        float4 v = make_float4(0.f, 0.f, 0.f, 0.f);
        if (idx < D_DIM) v = *(const float4*)(src + idx);   // D_DIM%4==0
        unsigned long long m0 = __ballot(v.x > 0.5f);
        unsigned long long m1 = __ballot(v.y > 0.5f);
        unsigned long long m2 = __ballot(v.z > 0.5f);
        unsigned long long m3 = __ballot(v.w > 0.5f);
        rs += (uint32_t)(__popcll(m0) + __popcll(m1) + __popcll(m2) + __popcll(m3));
        if (lane == 0) {
            uint4 p0, p1;
            p0.x = (uint32_t)m0; p0.y = (uint32_t)(m0 >> 32);
            p0.z = (uint32_t)m1; p0.w = (uint32_t)(m1 >> 32);
            p1.x = (uint32_t)m2; p1.y = (uint32_t)(m2 >> 32);
            p1.z = (uint32_t)m3; p1.w = (uint32_t)(m3 >> 32);
            *(uint4*)(dst + (size_t)w * 4)     = p0;
            *(uint4*)(dst + (size_t)w * 4 + 2) = p1;
        }
    }
    if (lane == 0) *rsw = rs;
}

// ---------------------------------------------------------------------------
// Kernel 2: dot01 GEMM on matrix cores (v_mfma_i32_32x32x32_i8, {0,1} bytes).
// Block: 256 thr (4 waves, 2x2), tile 128x128; wave tile 64x64 = 2x2 accs.
// Grid 64x8 = 512 blocks (2/CU). K: 20 chunks of 512 dims.
// LDS: paired-transpose [pair][row][2] (b64 reads 2-way/bcast = free; proven).
// Serial-sum evidence from v4/v5 (chunk time == MFMA+VALU+LDS summed, not
// max'd) -> this version pipelines at source level:
//   - pair i+1's 4 ds_read_b64 issued before pair i's compute (2 reg sets,
//     statically indexed after full unroll)
//   - UNP interleaved between MFMAs (indep UNPs fill the 36-cyc MFMA pipe)
//   - s_setprio(1) during compute cluster (T5; waves now role-diverse)
//   - per-wave pair order skew (start at pair 2w; integer acc order-free)
// ---------------------------------------------------------------------------
__global__ __launch_bounds__(256) void hd_kernel(
    const uint32_t* __restrict__ pA, const uint32_t* __restrict__ pB,
    const uint32_t* __restrict__ rsA, const uint32_t* __restrict__ rsB,
    float* __restrict__ out)
{
    __shared__ uint32_t AsT[2][(BKW / 2) * 256];   // [buf][pair*256 + row*2 + sub]
    __shared__ uint32_t BsT[2][(BKW / 2) * 256];

    const int tid  = threadIdx.x;
    const int row0 = blockIdx.x * 128;       // 64 row tiles
    const int col0 = blockIdx.y * 128;       // 8 col tiles (1024 padded)

    const int w    = tid >> 6;               // wave 0..3
    const int lane = tid & 63;
    const int wy   = w >> 1;                 // wave row half (64 rows)
    const int wx   = w & 1;                  // wave col half (64 cols)
    const int ln   = lane & 31;              // row/col within 32-tile
    const int h4   = (lane >> 5) * 4;        // k-half shift base
    const int pb   = 2 * w;                  // pair-order skew base

    // Staging roles: thread covers row srow = tid>>1, 32B half sq2 = (tid&1)*2.
    const int srow = tid >> 1;               // 0..127
    const int sq2  = (tid & 1) * 2;          // quad base 0 or 2
    const uint32_t* gAs = pA + (size_t)(row0 + srow) * W32P + sq2 * 4;
    int gc = col0 + srow; if (gc >= C_CLS) gc = C_CLS - 1;  // clamped cols never stored
    const uint32_t* gBs = pB + (size_t)gc * W32P + sq2 * 4;

    uint4 av[2], bv[2];                      // in-flight staging regs (T14)

#define LOADR(ch) do {                                             \
    av[0] = *(const uint4*)(gAs + (ch) * BKW);                     \
    av[1] = *(const uint4*)(gAs + (ch) * BKW + 4);                 \
    bv[0] = *(const uint4*)(gBs + (ch) * BKW);                     \
    bv[1] = *(const uint4*)(gBs + (ch) * BKW + 4);                 \
} while (0)

    // thread's 8 steps = sq2*4 + 0..7 -> pairs sq2*2 + i (i=0..3)
#define WRITELDS(buf) do {                                         \
    uint32_t* ap_ = &AsT[buf][sq2 * 512 + srow * 2];               \
    *(uint2*)(ap_      ) = make_uint2(av[0].x, av[0].y);           \
    *(uint2*)(ap_ + 256) = make_uint2(av[0].z, av[0].w);           \
    *(uint2*)(ap_ + 512) = make_uint2(av[1].x, av[1].y);           \
    *(uint2*)(ap_ + 768) = make_uint2(av[1].z, av[1].w);           \
    uint32_t* bp_ = &BsT[buf][sq2 * 512 + srow * 2];               \
    *(uint2*)(bp_      ) = make_uint2(bv[0].x, bv[0].y);           \
    *(uint2*)(bp_ + 256) = make_uint2(bv[0].z, bv[0].w);           \
    *(uint2*)(bp_ + 512) = make_uint2(bv[1].x, bv[1].y);           \
    *(uint2*)(bp_ + 768) = make_uint2(bv[1].z, bv[1].w);           \
} while (0)

    // bit-word -> 16 x i8 {0,1} fragment (lane's k-half selected by h4)
#define UNP(dst, src) do {                                         \
    dst[0] = (int)(((src) >> (h4 + 0)) & 0x01010101u);             \
    dst[1] = (int)(((src) >> (h4 + 1)) & 0x01010101u);             \
    dst[2] = (int)(((src) >> (h4 + 2)) & 0x01010101u);             \
    dst[3] = (int)(((src) >> (h4 + 3)) & 0x01010101u);             \
} while (0)

    // one K=32 step: fine UNP/MFMA interleave (indep UNPs under MFMA pipe)
#define STEP(wa0_, wa1_, wb0_, wb1_) do {                          \
    v4i a0_, a1_, b0_, b1_;                                        \
    UNP(a0_, wa0_); UNP(b0_, wb0_);                                \
    acc00 = __builtin_amdgcn_mfma_i32_32x32x32_i8(a0_, b0_, acc00, 0, 0, 0); \
    UNP(b1_, wb1_);                                                \
    acc01 = __builtin_amdgcn_mfma_i32_32x32x32_i8(a0_, b1_, acc01, 0, 0, 0); \
    UNP(a1_, wa1_);                                                \
    acc10 = __builtin_amdgcn_mfma_i32_32x32x32_i8(a1_, b0_, acc10, 0, 0, 0); \
    acc11 = __builtin_amdgcn_mfma_i32_32x32x32_i8(a1_, b1_, acc11, 0, 0, 0); \
} while (0)

#define LOADP(set, p) do {                                         \
    ra0[set] = *(const uint2*)&Ac[(p) * 256 + (wy * 64 + ln) * 2];        \
    ra1[set] = *(const uint2*)&Ac[(p) * 256 + (wy * 64 + 32 + ln) * 2];   \
    rb0[set] = *(const uint2*)&Bc[(p) * 256 + (wx * 64 + ln) * 2];        \
    rb1[set] = *(const uint2*)&Bc[(p) * 256 + (wx * 64 + 32 + ln) * 2];   \
} while (0)

    v16i acc00 = {}, acc01 = {}, acc10 = {}, acc11 = {};

    LOADR(0);
    WRITELDS(0);
    __syncthreads();

    #pragma unroll 2
    for (int ch = 0; ch < NCHUNK; ++ch) {
        const int cur = ch & 1;
        if (ch + 1 < NCHUNK) LOADR(ch + 1);   // issue early; consumed after compute

        const uint32_t* Ac = &AsT[cur][0];
        const uint32_t* Bc = &BsT[cur][0];

        uint2 ra0[2], ra1[2], rb0[2], rb1[2];
        LOADP(0, pb & 7);                      // prologue: pair 0 of this wave's order

        #pragma unroll
        for (int i = 0; i < 8; ++i) {          // fully unrolled: set idx static
            const int c = i & 1, n = c ^ 1;
            if (i < 7) LOADP(n, (pb + i + 1) & 7);   // next pair in flight
            __builtin_amdgcn_s_setprio(1);
            STEP(ra0[c].x, ra1[c].x, rb0[c].x, rb1[c].x);
            STEP(ra0[c].y, ra1[c].y, rb0[c].y, rb1[c].y);
            __builtin_amdgcn_s_setprio(0);
        }

        if (ch + 1 < NCHUNK) {
            WRITELDS((ch + 1) & 1);   // other buffer: disjoint from cur readers
            __syncthreads();          // writes visible before next chunk's reads
        }
    }
#undef LOADR
#undef WRITELDS
#undef UNP
#undef STEP
#undef LOADP

    // ---- epilogue: dist = rsA + rsB - 2*dot01, exact integer -> f32.
    // C/D layout (32x32): col = lane&31, row = (r&3) + 8*(r>>2) + 4*(lane>>5)
    const int gcol0 = col0 + wx * 64 + ln;
    const int gcol1 = gcol0 + 32;
    const uint32_t rb0v = (gcol0 < C_CLS) ? rsB[gcol0] : 0u;
    const uint32_t rb1v = (gcol1 < C_CLS) ? rsB[gcol1] : 0u;
    #pragma unroll
    for (int r = 0; r < 16; ++r) {
        const int m    = (r & 3) + 8 * (r >> 2) + h4;
        const int rowa = row0 + wy * 64 + m;         // tiles (0,*)
        const int rowb = rowa + 32;                  // tiles (1,*)
        const uint32_t ra0v = rsA[rowa];
        const uint32_t ra1v = rsA[rowb];
        if (gcol0 < C_CLS) {
            out[(size_t)rowa * C_CLS + gcol0] =
                (float)(int)(ra0v + rb0v - 2u * (uint32_t)acc00[r]);
            out[(size_t)rowb * C_CLS + gcol0] =
                (float)(int)(ra1v + rb0v - 2u * (uint32_t)acc10[r]);
        }
        if (gcol1 < C_CLS) {
            out[(size_t)rowa * C_CLS + gcol1] =
                (float)(int)(ra0v + rb1v - 2u * (uint32_t)acc01[r]);
            out[(size_t)rowb * C_CLS + gcol1] =
                (float)(int)(ra1v + rb1v - 2u * (uint32_t)acc11[r]);
        }
    }
}

extern "C" void kernel_launch(void* const* d_in, const int* in_sizes, int n_in,
                              void* d_out, int out_size, void* d_ws, size_t ws_size,
                              hipStream_t stream) {
    const float* samples = (const float*)d_in[0];   // [8192, 10000] f32
    const float* classes = (const float*)d_in[1];   // [1000, 10000] f32
    float* out = (float*)d_out;                     // [8192, 1000] f32

    // Workspace: packed A (10.49 MB), packed B (1.28 MB), rowsums (36.8 KB).
    unsigned long long* pA = (unsigned long long*)d_ws;
    unsigned long long* pB = pA + (size_t)N_ROWS * W64P;
    uint32_t* rsA = (uint32_t*)(pB + (size_t)C_CLS * W64P);
    uint32_t* rsB = rsA + N_ROWS;

    int waves  = N_ROWS + C_CLS;
    int blocks = (waves + 3) / 4;
    pack_kernel<<<blocks, 256, 0, stream>>>(samples, classes, pA, pB, rsA, rsB);

    dim3 grid(N_ROWS / 128, 8);              // 512 blocks (2 per CU)
    hd_kernel<<<grid, 256, 0, stream>>>((const uint32_t*)pA, (const uint32_t*)pB,
                                        rsA, rsB, out);
}